// Round 1
// 519.503 us; speedup vs baseline: 1.1276x; 1.1276x over previous
//
#include <hip/hip_runtime.h>
#include <math.h>

#define BB 8192
#define TT 60
#define NU 100
#define NI 7

typedef float v2f __attribute__((ext_vector_type(2)));
typedef float v4f __attribute__((ext_vector_type(4)));

// lane l (<50) owns unit pair (2l, 2l+1). Weights are k-packed:
// wa_j = {W[2l][2j], W[2l][2j+1]}, wb_j = {W[2l+1][2j], W[2l+1][2j+1]}
// (100 v2f = 200 arch VGPRs, same budget as before, contiguous loads).
//
// y-broadcast: instead of 100 v_readlane + ~100 splat movs per step (the
// old scheme — ~300 VALU/step measured via VALUBusy arithmetic), each lane
// publishes its yy pair with ONE ds_write_b64, then the wave does 25
// uniform-address ds_read_b128 (hardware broadcast, DS pipe, conflict-free).
// Each b128 yields two aligned v2f y-pairs consumed directly by
// v_pk_fma_f32 — zero broadcast VALU overhead.
#define FOR50(M) M(0) M(1) M(2) M(3) M(4) M(5) M(6) M(7) M(8) M(9) \
  M(10) M(11) M(12) M(13) M(14) M(15) M(16) M(17) M(18) M(19) \
  M(20) M(21) M(22) M(23) M(24) M(25) M(26) M(27) M(28) M(29) \
  M(30) M(31) M(32) M(33) M(34) M(35) M(36) M(37) M(38) M(39) \
  M(40) M(41) M(42) M(43) M(44) M(45) M(46) M(47) M(48) M(49)

// M(j2, ja, jb): j2 = v4f index in LDS, ja = 2*j2, jb = 2*j2+1 (k-pair idx)
#define FOR25(M) M(0,0,1) M(1,2,3) M(2,4,5) M(3,6,7) M(4,8,9) \
  M(5,10,11) M(6,12,13) M(7,14,15) M(8,16,17) M(9,18,19) \
  M(10,20,21) M(11,22,23) M(12,24,25) M(13,26,27) M(14,28,29) \
  M(15,30,31) M(16,32,33) M(17,34,35) M(18,36,37) M(19,38,39) \
  M(20,40,41) M(21,42,43) M(22,44,45) M(23,46,47) M(24,48,49)

// k-packed weight decls: contiguous v2f loads from each owned row
#define DECLW(j) \
  const v2f wa_##j = rowA[j]; \
  const v2f wb_##j = rowB[j];

// MAC over one v4f of broadcast y (4 k values): 4 independent pk_fma chains
#define MAC2(j2, ja, jb) { \
  const v4f y4 = Yv[j2]; \
  const v2f ylo = { y4.x, y4.y }; \
  const v2f yhi = { y4.z, y4.w }; \
  accA0 += ylo * wa_##ja; \
  accB0 += ylo * wb_##ja; \
  accA1 += yhi * wa_##jb; \
  accB1 += yhi * wb_##jb; }

#define RL(v,l) __int_as_float(__builtin_amdgcn_readlane(__float_as_int(v), l))

// DPP add-reduce step: part += dpp_move(part, ctrl) (pure VALU, no LDS)
#define DPPADD(ctrl, rmask) { \
  const int _t = __builtin_amdgcn_update_dpp(0, __float_as_int(part), (ctrl), (rmask), 0xf, false); \
  part += __int_as_float(_t); }

__global__ __launch_bounds__(256, 1)
void drr_kernel(const float* __restrict__ y0,
                const float* __restrict__ noise,
                const int*   __restrict__ stim_idx,
                const int*   __restrict__ rew_idx,
                const int*   __restrict__ instr_in,
                const float* __restrict__ W_in_raw,
                const float* __restrict__ W_rec,
                const float* __restrict__ b_rec,
                const float* __restrict__ w_out,
                const float* __restrict__ b_out,
                float* __restrict__ out)
{
    const int lane  = threadIdx.x & 63;
    const int wid   = threadIdx.x >> 6;
    const int trial = blockIdx.x * 4 + wid;

    const bool act = (lane < 50);              // active unit-pair lanes
    const int  la  = act ? lane : 49;          // clamped
    const int  ua  = 2 * la;                   // first unit
    const int  uao = ua * NU;

    // per-trial scalars (wave-uniform)
    const int  stim    = stim_idx[trial];
    const int  rew     = rew_idx[trial];
    const bool is_rew  = (stim == rew);
    const bool instr_b = (instr_in[trial] > 0);

    // k-packed weight registers: row ua and row ua+1, contiguous v2f
    const v2f* rowA = (const v2f*)(W_rec + uao);
    const v2f* rowB = rowA + (NU / 2);
    FOR50(DECLW)

    // W_in columns (abs applied), packed per unit pair
    const v2f wi6 = { fabsf(W_in_raw[ua * NI + 6]),    fabsf(W_in_raw[(ua+1) * NI + 6]) };
    const v2f wis = { fabsf(W_in_raw[ua * NI + stim]), fabsf(W_in_raw[(ua+1) * NI + stim]) };
    const v2f wr  = { fabsf(W_in_raw[ua * NI + 4]),    fabsf(W_in_raw[(ua+1) * NI + 4]) };
    const v2f wl  = { fabsf(W_in_raw[ua * NI + 5]),    fabsf(W_in_raw[(ua+1) * NI + 5]) };
    const v2f br  = { b_rec[ua], b_rec[ua + 1] };
    const v2f wo  = act ? (v2f){ w_out[ua], w_out[ua + 1] } : (v2f){ 0.0f, 0.0f };
    const float bo = b_out[0];

    const v2f* y0v = (const v2f*)(y0 + trial * NU);
    v2f yy = y0v[la];

    const float NS = 0.09486832980505138f; // 0.15 * sqrt(2*0.2)

    bool licked = false, instr_fired = false;
    int  lick_t = TT + 1;

    const float* nbase = noise + trial * (TT * NU);
    v2f en = ((const v2f*)nbase)[la];          // t=0 prefetch (8B load)

    // y broadcast buffer: 25 v4f used per wave, padded to 32 (512 B/wave)
    __shared__ v4f lds_y[4][32];
    v2f*       yw = (v2f*)&lds_y[wid][0];
    const v4f* Yv = &lds_y[wid][0];

    // output section pointers (flat tuple order)
    float* uout  = out;                        // B*T*7
    float* tout  = out  + BB * TT * NI;        // B*T
    float* rout  = tout + BB * TT;             // B*T
    float* lout  = rout + BB * TT;             // B
    float* dout  = lout + BB;                  // B
    float* zout  = dout + BB;                  // B*T
    float* yfout = zout + BB * TT;             // B*100

    for (int t = 0; t < TT; ++t) {
        // publish current y to this wave's LDS strip (lanes>=50 duplicate
        // lane 49's identical value — benign). Wave-local: no barrier,
        // compiler orders write->reads via lgkmcnt.
        yw[la] = yy;

        const v2f e = en;
        if (t < TT - 1)
            en = ((const v2f*)(nbase + (t + 1) * NU))[la];

        const float sm = (t >= 10 && t < 15) ? 1.0f : 0.0f;  // stim_mask
        const float rm = (t >= 20 && t < 35) ? 1.0f : 0.0f;  // resp_mask

        // reward routing (state from previous step), wave-uniform
        const bool delivered    = instr_fired || (licked && is_rew);
        const bool fire         = instr_b && !delivered && (t == 30);
        instr_fired             = instr_fired || fire;
        const bool instr_active = instr_fired && (t >= 30) && (t < 35);
        const bool lick_dyn     = licked && (t > lick_t) && (t < lick_t + 5);
        const float a_rew  = (instr_active ? 1.0f : 0.0f) + ((lick_dyn && is_rew) ? 1.0f : 0.0f);
        const float a_lick = lick_dyn ? 1.0f : 0.0f;

        // per-unit base (unit-packed v2f), added after the k-reduction
        const v2f base = br + rm * wi6 + sm * wis + a_rew * wr + a_lick * wl + NS * e;

        v2f accA0 = { 0.0f, 0.0f };
        v2f accA1 = { 0.0f, 0.0f };
        v2f accB0 = { 0.0f, 0.0f };
        v2f accB1 = { 0.0f, 0.0f };

        FOR25(MAC2)   // 25 uniform ds_read_b128 + 100 pk_fma, no readlane

        const v2f sA  = accA0 + accA1;
        const v2f sB  = accB0 + accB1;
        const v2f pre = base + (v2f){ sA.x + sA.y, sB.x + sB.y };
        const v2f prer = { fmaxf(pre.x, 0.0f), fmaxf(pre.y, 0.0f) };
        yy = 0.8f * yy + 0.2f * prer;

        // z = sigmoid(y . w_out + b_out) — DPP wave64 reduction (no LDS):
        // row_shr 1/2/4/8 -> row sums at lane 15 of each row;
        // row_bcast15 (rows 1,3) ; row_bcast31 (rows 2,3) -> lane 63 = total.
        float part = yy.x * wo.x + yy.y * wo.y;
        DPPADD(0x111, 0xf)   // row_shr:1
        DPPADD(0x112, 0xf)   // row_shr:2
        DPPADD(0x114, 0xf)   // row_shr:4
        DPPADD(0x118, 0xf)   // row_shr:8
        DPPADD(0x142, 0xa)   // row_bcast:15 -> rows 1,3
        DPPADD(0x143, 0xc)   // row_bcast:31 -> rows 2,3
        const float x = RL(part, 63) + bo;     // uniform via SGPR
        const float z = 1.0f / (1.0f + expf(-x));

        const bool in_resp = (t >= 20) && (t < 35);
        const bool trig    = in_resp && !licked && (z > 0.5f);
        if (trig) lick_t = t;          // wave-uniform
        licked = licked || trig;
        const bool u5 = licked && (t >= lick_t) && (t < lick_t + 5);
        const bool u4 = instr_active || (u5 && is_rew);

        // per-step outputs
        const int bt = trial * TT + t;
        if (lane < NI) {
            float uv = 0.0f;
            if (lane == stim) uv = sm;                 // stim in [0,4)
            if (lane == 4)    uv = u4 ? 1.0f : 0.0f;
            if (lane == 5)    uv = u5 ? 1.0f : 0.0f;
            if (lane == 6)    uv = rm;
            uout[bt * NI + lane] = uv;
        } else if (lane == 8) {
            tout[bt] = is_rew ? rm : 0.0f;
        } else if (lane == 9) {
            rout[bt] = rm;
        } else if (lane == 10) {
            zout[bt] = z;
        }
    }

    if (lane == 0) {
        lout[trial] = licked ? 1.0f : 0.0f;
        dout[trial] = (instr_fired || (licked && is_rew)) ? 1.0f : 0.0f;
    }
    if (act)
        ((v2f*)(yfout + trial * NU))[la] = yy;   // 8B store, units 2l/2l+1
}

extern "C" void kernel_launch(void* const* d_in, const int* in_sizes, int n_in,
                              void* d_out, int out_size, void* d_ws, size_t ws_size,
                              hipStream_t stream) {
    const float* y0       = (const float*)d_in[0];
    const float* noise    = (const float*)d_in[1];
    const int*   stim     = (const int*)  d_in[2];
    const int*   rew      = (const int*)  d_in[3];
    const int*   instr    = (const int*)  d_in[4];
    const float* W_in_raw = (const float*)d_in[5];
    const float* W_rec    = (const float*)d_in[6];
    const float* b_rec    = (const float*)d_in[7];
    const float* w_out    = (const float*)d_in[8];
    const float* b_out    = (const float*)d_in[9];
    float* out = (float*)d_out;

    drr_kernel<<<BB / 4, 256, 0, stream>>>(y0, noise, stim, rew, instr,
                                           W_in_raw, W_rec, b_rec, w_out, b_out, out);
}